// Round 1
// baseline (348.762 us; speedup 1.0000x reference)
//
#include <hip/hip_runtime.h>

#define DIN 24
#define DOUT 47
#define CIN 32
#define COUT 64
#define SP_IN (DIN*DIN*DIN)        // 13824
#define SP_OUT (DOUT*DOUT*DOUT)    // 103823
#define NCO 4
#define KVOL 27
#define W_PER_CO (CIN*KVOL)        // 864
#define GROUPS 8

// spatial decode constants: (od,oh) parity regions x 3 ow-tiles of 16
// R00: 24*24*3=1728, R01: 24*23*3=1656, R10: 23*24*3=1656, R11: 23*23*3=1587
#define NTHREAD_SP 6627            // total per (n, co-tile)

__device__ __forceinline__ float hswish(float z) {
    float c = fminf(fmaxf(z + 3.f, 0.f), 6.f);
    return z * c * (1.f / 6.f);
}

__global__ __launch_bounds__(256)
void conv_swish_stats(const float* __restrict__ x,
                      const float* __restrict__ w,
                      const float* __restrict__ bias,
                      float* __restrict__ y,
                      float* __restrict__ stats)
{
    const int co0 = blockIdx.y * NCO;
    const int n = blockIdx.z;

    // packed weights: [q][ci][kdh][4], slot 3 unused (16B-aligned ds_read_b128)
    __shared__ float wl[NCO * CIN * 9 * 4];
    for (int i = threadIdx.x; i < NCO * W_PER_CO; i += 256) {
        int q = i / W_PER_CO;
        int rem = i - q * W_PER_CO;
        int ci = rem / KVOL;
        int k = rem - ci * KVOL;
        int kdh = k / 3;
        int kw = k - kdh * 3;
        wl[((q * CIN + ci) * 9 + kdh) * 4 + kw] = w[co0 * W_PER_CO + i];
    }
    __syncthreads();

    int s = blockIdx.x * 256 + threadIdx.x;
    const bool active = (s < NTHREAD_SP);
    if (!active) s = NTHREAD_SP - 1;

    int od, oh, tw;
    {
        int u, r;
        if (s < 1728)      { u = s;        tw = u % 3; r = u / 3; oh = (r % 24) * 2;     od = (r / 24) * 2; }
        else if (s < 3384) { u = s - 1728; tw = u % 3; r = u / 3; oh = (r % 23) * 2 + 1; od = (r / 23) * 2; }
        else if (s < 5040) { u = s - 3384; tw = u % 3; r = u / 3; oh = (r % 24) * 2;     od = (r / 24) * 2 + 1; }
        else               { u = s - 5040; tw = u % 3; r = u / 3; oh = (r % 23) * 2 + 1; od = (r / 23) * 2 + 1; }
    }
    const int ow0 = tw * 16;
    const int t = tw * 8;               // base input-w index
    const bool xs8_ok = (tw != 2);      // t+8==24 would be OOB on last tile

    float acc[NCO][16];
    #pragma unroll
    for (int q = 0; q < NCO; ++q)
        #pragma unroll
        for (int j = 0; j < 16; ++j) acc[q][j] = 0.f;

    const float* xb = x + (size_t)n * CIN * SP_IN;
    const float4* wl4 = (const float4*)wl;

    #pragma unroll
    for (int kd = 0; kd < 3; ++kd) {
        int ud = od + 1 - kd;
        if (ud & 1) continue;           // wave-uniform (parity regions)
        int id = ud >> 1;               // always in [0,24)
        #pragma unroll
        for (int kh = 0; kh < 3; ++kh) {
            int uh = oh + 1 - kh;
            if (uh & 1) continue;       // wave-uniform
            int ih = uh >> 1;
            const float* xp = xb + (id * DIN + ih) * DIN + t;
            const int kdh = kd * 3 + kh;
            for (int ci = 0; ci < CIN; ++ci) {
                // xp is 32B-aligned: row base multiple of 24 floats, t multiple of 8
                const float4* xp4 = (const float4*)xp;
                float4 xa = xp4[0];
                float4 xc = xp4[1];
                float xs[9];
                xs[0] = xa.x; xs[1] = xa.y; xs[2] = xa.z; xs[3] = xa.w;
                xs[4] = xc.x; xs[5] = xc.y; xs[6] = xc.z; xs[7] = xc.w;
                xs[8] = xs8_ok ? xp[8] : 0.f;
                #pragma unroll
                for (int q = 0; q < NCO; ++q) {
                    float4 wv = wl4[(q * CIN + ci) * 9 + kdh];  // .x=kw0 .y=kw1 .z=kw2
                    #pragma unroll
                    for (int j = 0; j < 16; j += 2) {
                        const int h = j >> 1;
                        // even ow: kw=1, iw=t+h ; odd ow: kw=0 -> iw=t+h+1, kw=2 -> iw=t+h
                        acc[q][j]     = fmaf(xs[h],     wv.y, acc[q][j]);
                        acc[q][j + 1] = fmaf(xs[h + 1], wv.x, fmaf(xs[h], wv.z, acc[q][j + 1]));
                    }
                }
                xp += SP_IN;
            }
        }
    }

    float s1 = 0.f, s2 = 0.f;
    if (active) {
        const bool last_ok = (ow0 + 15) < DOUT;   // only tile 2 drops j=15
        #pragma unroll
        for (int q = 0; q < NCO; ++q) {
            const float bq = bias[co0 + q];
            float* yp = y + ((size_t)(n * COUT + co0 + q)) * SP_OUT
                          + (od * DOUT + oh) * DOUT + ow0;
            #pragma unroll
            for (int j = 0; j < 16; ++j) {
                if (j == 15 && !last_ok) continue;
                float v = acc[q][j] + bq;
                float sw = v / (1.f + __expf(-v));   // swish
                yp[j] = sw;
                s1 += sw;
                s2 += sw * sw;
            }
        }
    }

    // block reduce -> one atomicAdd pair per block into (n,g) bucket
    #pragma unroll
    for (int off = 32; off > 0; off >>= 1) {
        s1 += __shfl_down(s1, off);
        s2 += __shfl_down(s2, off);
    }
    __shared__ float r1[4], r2[4];
    const int wid = threadIdx.x >> 6;
    if ((threadIdx.x & 63) == 0) { r1[wid] = s1; r2[wid] = s2; }
    __syncthreads();
    if (threadIdx.x == 0) {
        const int g = co0 >> 3;
        atomicAdd(&stats[(n * GROUPS + g) * 2 + 0], r1[0] + r1[1] + r1[2] + r1[3]);
        atomicAdd(&stats[(n * GROUPS + g) * 2 + 1], r2[0] + r2[1] + r2[2] + r2[3]);
    }
}

__global__ __launch_bounds__(256)
void norm_hswish(float* __restrict__ y, const float* __restrict__ stats)
{
    const int total4 = (8 * COUT * SP_OUT) / 4;     // 13289344
    const int grp4   = (8 * SP_OUT) / 4;            // 207646 float4 per (n,g)
    const float inv_cnt = 1.0f / (8.0f * (float)SP_OUT);
    float4* p = (float4*)y;
    int idx = blockIdx.x * 256 + threadIdx.x;
    const int stride = gridDim.x * 256;
    for (int i = idx; i < total4; i += stride) {
        const int ng = i / grp4;                    // float4 never straddles a group
        const float m1 = stats[ng * 2 + 0] * inv_cnt;
        const float m2 = stats[ng * 2 + 1] * inv_cnt;
        const float var = m2 - m1 * m1;
        const float rstd = rsqrtf(var + 1e-5f);
        float4 v = p[i];
        v.x = hswish((v.x - m1) * rstd);
        v.y = hswish((v.y - m1) * rstd);
        v.z = hswish((v.z - m1) * rstd);
        v.w = hswish((v.w - m1) * rstd);
        p[i] = v;
    }
}

extern "C" void kernel_launch(void* const* d_in, const int* in_sizes, int n_in,
                              void* d_out, int out_size, void* d_ws, size_t ws_size,
                              hipStream_t stream)
{
    const float* x    = (const float*)d_in[0];
    const float* w    = (const float*)d_in[1];
    const float* bias = (const float*)d_in[2];
    float* y     = (float*)d_out;
    float* stats = (float*)d_ws;

    hipMemsetAsync(d_ws, 0, 8 * GROUPS * 2 * sizeof(float), stream);

    dim3 grid1((NTHREAD_SP + 255) / 256, COUT / NCO, 8);   // (26, 16, 8)
    conv_swish_stats<<<grid1, 256, 0, stream>>>(x, w, bias, y, stats);

    norm_hswish<<<2048, 256, 0, stream>>>(y, stats);
}